// Round 1
// 399.236 us; speedup vs baseline: 1.0004x; 1.0004x over previous
//
#include <hip/hip_runtime.h>
#include <hip/hip_bf16.h>
#include <math.h>

#define Bq 256
#define Tq 256
#define Hq 512
#define Eq 96

typedef __attribute__((ext_vector_type(8))) short short8;
typedef __attribute__((ext_vector_type(4))) float f32x4;

static __device__ __forceinline__ unsigned short f2bf(float f) {
  union { float f; unsigned u; } v; v.f = f;
  unsigned r = v.u + 0x7FFF + ((v.u >> 16) & 1);
  return (unsigned short)(r >> 16);
}

static __device__ __forceinline__ ushort4 pack4(float4 v) {
  ushort4 p;
  p.x = f2bf(v.x); p.y = f2bf(v.y); p.z = f2bf(v.z); p.w = f2bf(v.w);
  return p;
}

static __device__ __forceinline__ float sat_tanh(float x) {
  float ax = fminf(fabsf(x), 15.0f);
  float e = __builtin_exp2f(ax * 2.885390082f);
  float t = 1.0f - 2.0f / (e + 1.0f);
  return copysignf(t, x);
}

static __device__ __forceinline__ float sat_sig(float x) {
  float cx = fmaxf(fminf(x, 30.0f), -30.0f);
  return 1.0f / (1.0f + __builtin_exp2f(-cx * 1.442695041f));
}

// ---------------- K0: W_i2h fp32 [K][N] -> bf16 transposed [N][K] ----------
__global__ __launch_bounds__(256) void convW_k(const float* __restrict__ W,
                                               unsigned short* __restrict__ Wt) {
  __shared__ float tile[32][33];
  int bx = blockIdx.x & 15, by = blockIdx.x >> 4;
  int tx = threadIdx.x & 31, ty = threadIdx.x >> 5;
  #pragma unroll
  for (int i = 0; i < 32; i += 8)
    tile[ty + i][tx] = W[(size_t)(by * 32 + ty + i) * Hq + bx * 32 + tx];
  __syncthreads();
  #pragma unroll
  for (int i = 0; i < 32; i += 8)
    Wt[(size_t)(bx * 32 + ty + i) * Hq + by * 32 + tx] = f2bf(tile[tx][ty + i]);
}

// ---------------- K1: hp partial GEMM, K-split, atomicAdd ------------------
__global__ __launch_bounds__(256) void hsplit_k(const float* __restrict__ ph,
                                                const float* __restrict__ Whh,
                                                float* __restrict__ hp) {
  __shared__ __align__(16) float xs[8][128];
  const int ks = blockIdx.x & 3;
  const int nc = (blockIdx.x >> 2) & 3;
  const int bg = blockIdx.x >> 4;
  const int tid = threadIdx.x;
  const int row0 = bg * 8;
  const int d0 = ks * 128;
  for (int i = tid; i < 8 * 32; i += 256) {
    int r = i >> 5, dd = (i & 31) * 4;
    *(float4*)&xs[r][dd] = *(const float4*)&ph[(size_t)(row0 + r) * Hq + d0 + dd];
  }
  __syncthreads();
  const int rt = tid >> 6;
  const int ct = tid & 63;
  const int n = nc * 128 + ct * 2;
  float a00 = 0, a01 = 0, a10 = 0, a11 = 0;
  for (int dd = 0; dd < 128; dd += 4) {
    float4 x0 = *(const float4*)&xs[rt * 2][dd];
    float4 x1 = *(const float4*)&xs[rt * 2 + 1][dd];
    #pragma unroll
    for (int j = 0; j < 4; j++) {
      float2 w = *(const float2*)&Whh[(size_t)(d0 + dd + j) * Hq + n];
      float xj0 = ((const float*)&x0)[j];
      float xj1 = ((const float*)&x1)[j];
      a00 += xj0 * w.x; a01 += xj0 * w.y;
      a10 += xj1 * w.x; a11 += xj1 * w.y;
    }
  }
  int row = row0 + rt * 2;
  atomicAdd(&hp[(size_t)row * Hq + n], a00);
  atomicAdd(&hp[(size_t)row * Hq + n + 1], a01);
  atomicAdd(&hp[(size_t)(row + 1) * Hq + n], a10);
  atomicAdd(&hp[(size_t)(row + 1) * Hq + n + 1], a11);
}

// ---------------- K2: fused proj GEMM + tanh + w_score dot -> e ------------
// New structure: each block owns 64 rows x ALL 512 cols -> batch_H read ONCE.
// 4 waves, each owns a 128-col chunk (acc[4][8]). A staged fp32->bf16 via a
// tiny double-buffered LDS tile (one barrier / K-step, reg-prefetch of next
// tile). B fragments loaded straight from L2-resident Wt (512 KB, shared by
// all blocks) -- no B staging, no second barrier. e written once (LDS
// cross-wave reduce), no atomics -> no alpha memset.
#define LDK 40

__global__ __launch_bounds__(256, 2) void fused_score_k(
    const float* __restrict__ A,
    const unsigned short* __restrict__ Wt,
    const float* __restrict__ hp,
    const float* __restrict__ bh,
    const float* __restrict__ wsc,
    float* __restrict__ e) {
  __shared__ unsigned short As[2][64 * LDK];
  __shared__ float red[4][64];

  const int tid = threadIdx.x;
  const int m0 = blockIdx.x * 64;   // 64 rows of (b,t); b fixed per block
  const int b = m0 >> 8;
  const int wave = tid >> 6;
  const int lane = tid & 63;
  const int quad = lane >> 4;
  const int l16 = lane & 15;
  const int wn = wave * 128;        // wave's 128-col chunk

  const int arow = tid >> 3;        // 0..31 (staging row, +32 second pass)
  const int acol = (tid & 7) * 4;   // 0..28 (staging col, float4)
  const float* Ab = A + (size_t)m0 * Hq;
  const unsigned short* Bp = Wt + (size_t)(wn + l16) * Hq + quad * 8;

  f32x4 acc[4][8] = {};

  // prologue: stage k=0 into buffer 0
  {
    float4 v0 = *(const float4*)&Ab[(size_t)arow * Hq + acol];
    float4 v1 = *(const float4*)&Ab[(size_t)(arow + 32) * Hq + acol];
    *(ushort4*)&As[0][arow * LDK + acol] = pack4(v0);
    *(ushort4*)&As[0][(arow + 32) * LDK + acol] = pack4(v1);
  }
  __syncthreads();

  for (int step = 0; step < 16; step++) {
    const int k0 = step * 32;
    const int cur = step & 1;

    // prefetch next A tile into registers (hides HBM latency under MFMA)
    float4 n0v, n1v;
    if (step < 15) {
      n0v = *(const float4*)&Ab[(size_t)arow * Hq + k0 + 32 + acol];
      n1v = *(const float4*)&Ab[(size_t)(arow + 32) * Hq + k0 + 32 + acol];
    }

    // B fragments straight from global (L2-resident Wt)
    short8 bfr[8];
    #pragma unroll
    for (int ni = 0; ni < 8; ni++)
      bfr[ni] = *(const short8*)(Bp + (size_t)ni * 16 * Hq + k0);

    // A fragments from LDS (shared by all 4 waves)
    short8 af[4];
    #pragma unroll
    for (int mi = 0; mi < 4; mi++)
      af[mi] = *(const short8*)&As[cur][(mi * 16 + l16) * LDK + quad * 8];

    #pragma unroll
    for (int mi = 0; mi < 4; mi++)
      #pragma unroll
      for (int ni = 0; ni < 8; ni++)
        acc[mi][ni] = __builtin_amdgcn_mfma_f32_16x16x32_bf16(
            af[mi], bfr[ni], acc[mi][ni], 0, 0, 0);

    if (step < 15) {
      *(ushort4*)&As[cur ^ 1][arow * LDK + acol] = pack4(n0v);
      *(ushort4*)&As[cur ^ 1][(arow + 32) * LDK + acol] = pack4(n1v);
    }
    __syncthreads();
  }

  // epilogue: tanh + w_score dot over this wave's 128 cols
  float hv[8], wv[8];
  #pragma unroll
  for (int ni = 0; ni < 8; ni++) {
    int c = wn + ni * 16 + l16;
    hv[ni] = hp[(size_t)b * Hq + c] + bh[c];
    wv[ni] = wsc[c];
  }
  #pragma unroll
  for (int mi = 0; mi < 4; mi++) {
    float s[4] = {0, 0, 0, 0};
    #pragma unroll
    for (int ni = 0; ni < 8; ni++)
      #pragma unroll
      for (int r = 0; r < 4; r++)
        s[r] += sat_tanh(acc[mi][ni][r] + hv[ni]) * wv[ni];
    #pragma unroll
    for (int r = 0; r < 4; r++) {
      s[r] += __shfl_xor(s[r], 8, 64);
      s[r] += __shfl_xor(s[r], 4, 64);
      s[r] += __shfl_xor(s[r], 2, 64);
      s[r] += __shfl_xor(s[r], 1, 64);
    }
    if (l16 == 0) {
      #pragma unroll
      for (int r = 0; r < 4; r++) red[wave][mi * 16 + quad * 4 + r] = s[r];
    }
  }
  __syncthreads();
  if (tid < 64)
    e[m0 + tid] = red[0][tid] + red[1][tid] + red[2][tid] + red[3][tid];
}

// ---------------- K3: softmax over T per batch, IN PLACE -------------------
__global__ __launch_bounds__(256) void softmax_k(float* __restrict__ ea) {
  __shared__ float red[8];
  int b = blockIdx.x, t = threadIdx.x;
  int wave = t >> 6, lane = t & 63;
  float x = ea[b * Tq + t];
  float m = x;
  #pragma unroll
  for (int off = 32; off >= 1; off >>= 1) m = fmaxf(m, __shfl_xor(m, off, 64));
  if (lane == 0) red[wave] = m;
  __syncthreads();
  m = fmaxf(fmaxf(red[0], red[1]), fmaxf(red[2], red[3]));
  float ex = __builtin_exp2f((x - m) * 1.442695041f);
  float s = ex;
  #pragma unroll
  for (int off = 32; off >= 1; off >>= 1) s += __shfl_xor(s, off, 64);
  if (lane == 0) red[4 + wave] = s;
  __syncthreads();
  s = red[4] + red[5] + red[6] + red[7];
  ea[b * Tq + t] = ex / s;
}

// ---------------- K4: context partials, T-split, atomicAdd -----------------
__global__ __launch_bounds__(256) void ctxsplit_k(const float* __restrict__ alpha,
                                                  const float* __restrict__ bH,
                                                  float* __restrict__ ctx) {
  __shared__ float al[64];
  const int b = blockIdx.x >> 2;
  const int tc = blockIdx.x & 3;
  const int tid = threadIdx.x;
  if (tid < 64) al[tid] = alpha[b * Tq + tc * 64 + tid];
  __syncthreads();
  const float2* Hp = (const float2*)(bH + (size_t)b * Tq * Hq + (size_t)tc * 64 * Hq);
  float ax = 0.f, ay = 0.f;
  #pragma unroll 8
  for (int t = 0; t < 64; t++) {
    float a = al[t];
    float2 v = Hp[t * (Hq / 2) + tid];
    ax += a * v.x;
    ay += a * v.y;
  }
  atomicAdd(&ctx[(size_t)b * Hq + 2 * tid], ax);
  atomicAdd(&ctx[(size_t)b * Hq + 2 * tid + 1], ay);
}

// ---------------- K5a: z partial GEMM, K-split, atomicAdd ------------------
__global__ __launch_bounds__(256) void zsplit_k(
    const float* __restrict__ ctx, const float* __restrict__ oneh,
    const float* __restrict__ ph, const float* __restrict__ Wl,
    const float* __restrict__ Ul, float* __restrict__ z) {
  __shared__ __align__(16) float xs[8 * 280];
  const int ks = blockIdx.x & 3;
  const int hc = (blockIdx.x >> 2) & 7;
  const int bg = blockIdx.x >> 5;
  const int tid = threadIdx.x;
  const int row0 = bg * 8;
  const int dbase = ks * 280;

  for (int i = tid; i < 8 * 280; i += 256) {
    int r = i / 280, dd = i % 280;
    int g = dbase + dd;
    float v;
    if (g < 512) v = ctx[(size_t)(row0 + r) * Hq + g];
    else if (g < 608) v = oneh[(row0 + r) * Eq + (g - 512)];
    else v = ph[(size_t)(row0 + r) * Hq + (g - 608)];
    xs[r * 280 + dd] = v;
  }
  __syncthreads();

  const int rt = tid >> 6;
  const int ct = tid & 63;
  const int c0 = ct * 4;
  const int gate = c0 >> 6;
  const int ho = c0 & 63;
  const int n = gate * 512 + hc * 64 + ho;

  float acc0[4] = {0, 0, 0, 0};
  float acc1[4] = {0, 0, 0, 0};
  const float* xr0 = &xs[(rt * 2) * 280];
  const float* xr1 = &xs[(rt * 2 + 1) * 280];

  for (int dd = 0; dd < 280; dd += 4) {
    float4 x0 = *(const float4*)&xr0[dd];
    float4 x1 = *(const float4*)&xr1[dd];
    #pragma unroll
    for (int j = 0; j < 4; j++) {
      int d = dbase + dd + j;
      const float* wp = (d < 608) ? &Wl[(size_t)d * 2048 + n]
                                  : &Ul[(size_t)(d - 608) * 2048 + n];
      float4 w = *(const float4*)wp;
      float a = ((const float*)&x0)[j], b = ((const float*)&x1)[j];
      acc0[0] += a * w.x; acc0[1] += a * w.y; acc0[2] += a * w.z; acc0[3] += a * w.w;
      acc1[0] += b * w.x; acc1[1] += b * w.y; acc1[2] += b * w.z; acc1[3] += b * w.w;
    }
  }
  const int r0 = row0 + rt * 2;
  #pragma unroll
  for (int j = 0; j < 4; j++) {
    atomicAdd(&z[(size_t)r0 * 2048 + n + j], acc0[j]);
    atomicAdd(&z[(size_t)(r0 + 1) * 2048 + n + j], acc1[j]);
  }
}

// ---------------- K5b: gates from z ----------------------------------------
__global__ __launch_bounds__(256) void gatesz_k(const float* __restrict__ z,
                                                const float* __restrict__ bl,
                                                const float* __restrict__ pc,
                                                float* __restrict__ outh,
                                                float* __restrict__ outc) {
  int p = blockIdx.x * 256 + threadIdx.x;  // 0..65535
  #pragma unroll
  for (int q = 0; q < 2; q++, p += 65536) {
    int r = p >> 9, h = p & 511;
    const float* zb = z + (size_t)r * 2048;
    float gi = zb[h] + bl[h];
    float gf = zb[512 + h] + bl[512 + h];
    float gg = zb[1024 + h] + bl[1024 + h];
    float go = zb[1536 + h] + bl[1536 + h];
    float cn = sat_sig(gf) * pc[p] + sat_sig(gi) * sat_tanh(gg);
    float hn = sat_sig(go) * sat_tanh(cn);
    outh[p] = hn;
    outc[p] = cn;
  }
}

// ---------------- fallback K5 (ws too small for z): fused z-GEMM+gates -----
#define KXc 1120
__global__ __launch_bounds__(256) void zgates2_k(
    const float* __restrict__ ctx, const float* __restrict__ oneh,
    const float* __restrict__ ph, const float* __restrict__ pc,
    const float* __restrict__ Wl, const float* __restrict__ Ul,
    const float* __restrict__ bl,
    float* __restrict__ outh, float* __restrict__ outc) {
  __shared__ __align__(16) float xs[8 * KXc];
  const int bg = blockIdx.x >> 3;
  const int hc = blockIdx.x & 7;
  const int tid = threadIdx.x;
  const int row0 = bg * 8;

  for (int i = tid; i < 8 * 128; i += 256) {
    int r = i >> 7, dd = (i & 127) * 4;
    *(float4*)&xs[r * KXc + dd] = *(const float4*)&ctx[(size_t)(row0 + r) * Hq + dd];
  }
  for (int i = tid; i < 8 * 128; i += 256) {
    int r = i >> 7, dd = (i & 127) * 4;
    *(float4*)&xs[r * KXc + 608 + dd] = *(const float4*)&ph[(size_t)(row0 + r) * Hq + dd];
  }
  if (tid < 8 * 24) {
    int r = tid / 24, dd = (tid % 24) * 4;
    *(float4*)&xs[r * KXc + 512 + dd] = *(const float4*)&oneh[(row0 + r) * Eq + dd];
  }
  __syncthreads();

  const int rt = tid >> 6;
  const int ct = tid & 63;
  const int c0 = ct * 4;
  const int gate = c0 >> 6;
  const int ho = c0 & 63;
  const int n = gate * 512 + hc * 64 + ho;

  float acc0[4] = {0, 0, 0, 0};
  float acc1[4] = {0, 0, 0, 0};
  const float* xr0 = &xs[(rt * 2) * KXc];
  const float* xr1 = &xs[(rt * 2 + 1) * KXc];

  for (int d = 0; d < 608; d += 4) {
    float4 x0 = *(const float4*)&xr0[d];
    float4 x1 = *(const float4*)&xr1[d];
    #pragma unroll
    for (int j = 0; j < 4; j++) {
      float4 w = *(const float4*)&Wl[(size_t)(d + j) * 2048 + n];
      float a = ((const float*)&x0)[j], b = ((const float*)&x1)[j];
      acc0[0] += a * w.x; acc0[1] += a * w.y; acc0[2] += a * w.z; acc0[3] += a * w.w;
      acc1[0] += b * w.x; acc1[1] += b * w.y; acc1[2] += b * w.z; acc1[3] += b * w.w;
    }
  }
  for (int d = 0; d < 512; d += 4) {
    float4 x0 = *(const float4*)&xr0[608 + d];
    float4 x1 = *(const float4*)&xr1[608 + d];
    #pragma unroll
    for (int j = 0; j < 4; j++) {
      float4 w = *(const float4*)&Ul[(size_t)(d + j) * 2048 + n];
      float a = ((const float*)&x0)[j], b = ((const float*)&x1)[j];
      acc0[0] += a * w.x; acc0[1] += a * w.y; acc0[2] += a * w.z; acc0[3] += a * w.w;
      acc1[0] += b * w.x; acc1[1] += b * w.y; acc1[2] += b * w.z; acc1[3] += b * w.w;
    }
  }

  __syncthreads();
  float* zs = xs;
  #pragma unroll
  for (int j = 0; j < 4; j++) {
    zs[(rt * 2) * 256 + c0 + j] = acc0[j];
    zs[(rt * 2 + 1) * 256 + c0 + j] = acc1[j];
  }
  __syncthreads();

  #pragma unroll
  for (int p = tid; p < 512; p += 256) {
    int r = p >> 6, o = p & 63;
    int h = hc * 64 + o;
    int grow = row0 + r;
    float gi = zs[r * 256 + o]       + bl[h];
    float gf = zs[r * 256 + 64 + o]  + bl[512 + h];
    float gg = zs[r * 256 + 128 + o] + bl[1024 + h];
    float go = zs[r * 256 + 192 + o] + bl[1536 + h];
    float cn = sat_sig(gf) * pc[(size_t)grow * Hq + h] + sat_sig(gi) * sat_tanh(gg);
    float hn = sat_sig(go) * sat_tanh(cn);
    outh[(size_t)grow * Hq + h] = hn;
    outc[(size_t)grow * Hq + h] = cn;
  }
}

extern "C" void kernel_launch(void* const* d_in, const int* in_sizes, int n_in,
                              void* d_out, int out_size, void* d_ws, size_t ws_size,
                              hipStream_t stream) {
  const float* prev_h = (const float*)d_in[0];
  const float* prev_c = (const float*)d_in[1];
  const float* batch_H = (const float*)d_in[2];
  const float* oneh = (const float*)d_in[3];
  const float* W_i2h = (const float*)d_in[4];
  const float* W_h2h = (const float*)d_in[5];
  const float* b_h2h = (const float*)d_in[6];
  const float* w_score = (const float*)d_in[7];
  const float* W_lstm = (const float*)d_in[8];
  const float* U_lstm = (const float*)d_in[9];
  const float* b_lstm = (const float*)d_in[10];

  float* out = (float*)d_out;
  float* outh = out;
  float* outc = out + Bq * Hq;
  float* alpha = out + 2 * Bq * Hq;

  // ws layout: [0,512K) hp -> ctx; [512K,1M) Wt; z (2MB) overlays [512K,2.5M)
  float* ws = (float*)d_ws;
  float* hp = ws;
  float* ctx = ws;
  unsigned short* Wt = (unsigned short*)(ws + 131072);
  float* z = ws + 131072;  // 524288 floats, overlays Wt (dead by then)

  const bool bigws = ws_size >= 2621440;  // 2.5 MB needed for z path

  hipMemsetAsync(hp, 0, Bq * Hq * sizeof(float), stream);
  convW_k<<<256, 256, 0, stream>>>(W_i2h, Wt);
  hsplit_k<<<512, 256, 0, stream>>>(prev_h, W_h2h, hp);
  // e (alpha buffer) is fully written now -- no memset needed.
  fused_score_k<<<1024, 256, 0, stream>>>(batch_H, Wt, hp, b_h2h, w_score, alpha);
  softmax_k<<<256, 256, 0, stream>>>(alpha);
  if (bigws) {
    // zero ctx (512K) + z (2M) in one contiguous memset; Wt/hp dead now
    hipMemsetAsync(ws, 0, 2621440, stream);
    ctxsplit_k<<<1024, 256, 0, stream>>>(alpha, batch_H, ctx);
    zsplit_k<<<1024, 256, 0, stream>>>(ctx, oneh, prev_h, W_lstm, U_lstm, z);
    gatesz_k<<<256, 256, 0, stream>>>(z, b_lstm, prev_c, outh, outc);
  } else {
    hipMemsetAsync(ctx, 0, Bq * Hq * sizeof(float), stream);
    ctxsplit_k<<<1024, 256, 0, stream>>>(alpha, batch_H, ctx);
    zgates2_k<<<256, 256, 0, stream>>>(ctx, oneh, prev_h, prev_c,
                                       W_lstm, U_lstm, b_lstm, outh, outc);
  }
}